// Round 9
// baseline (339.277 us; speedup 1.0000x reference)
//
#include <hip/hip_runtime.h>

#define D 128
#define BN_EPS 1e-5f
#define ELLW 64             // max degree slots (Poisson(12.8): P(deg>64) ~ 1e-24)
#define SGRP 8              // stats accumulator groups (= #XCDs; blockIdx%8 ~ XCD)

typedef __bf16 bf16_t;
typedef __bf16 bf16x8 __attribute__((ext_vector_type(8)));
typedef __bf16 bf16x4 __attribute__((ext_vector_type(4)));
typedef float floatx4 __attribute__((ext_vector_type(4)));

// ===========================================================================
// prep: zero deg[N] + stats[3*SGRP*256], x fp32 -> hb bf16, swizzle weights
// to MFMA B-frag order. Grid covers n4 = N*D/4 (largest range).
// ===========================================================================
__global__ void prep(const float* __restrict__ x, bf16_t* __restrict__ hb,
                     const float* __restrict__ W1, const float* __restrict__ W2,
                     bf16_t* __restrict__ Wsw, int* __restrict__ deg,
                     float* __restrict__ stats, int N, int n4) {
  int i = blockIdx.x * blockDim.x + threadIdx.x;
  if (i < n4) {
    float4 v = ((const float4*)x)[i];
    bf16x4 p;
    p[0] = (bf16_t)v.x; p[1] = (bf16_t)v.y; p[2] = (bf16_t)v.z; p[3] = (bf16_t)v.w;
    *(bf16x4*)(hb + (size_t)4 * i) = p;
  }
  if (i < N) deg[i] = 0;
  if (i < 3 * SGRP * 256) stats[i] = 0.f;
  if (i < 6 * 16384) {
    // B-frag order: lane = quad*16 + (n&15) holds B[k=kc*32+quad*8+j][n]
    int mat = i >> 14;
    int kn = i & 16383;
    int k = kn >> 7;
    int n = kn & 127;
    const float* Wm = (mat < 3) ? (W1 + (size_t)mat * 16384)
                                : (W2 + (size_t)(mat - 3) * 16384);
    float v = Wm[kn];
    int f = ((n >> 4) << 2) | (k >> 5);
    int ln = (((k >> 3) & 3) << 4) | (n & 15);
    int j = k & 7;
    Wsw[(size_t)mat * 16384 + ((f << 6) + ln) * 8 + j] = (bf16_t)v;
  }
}

// ===========================================================================
// ell_fill: one-shot ELL build — atomic slot bump + native 4B scatter.
// ===========================================================================
__global__ void ell_fill(const int* __restrict__ src, const int* __restrict__ dst,
                         int* __restrict__ deg, int* __restrict__ ell, int E) {
  int e = blockIdx.x * blockDim.x + threadIdx.x;
  if (e < E) {
    int d = dst[e];
    int slot = atomicAdd(&deg[d], 1);
    if (slot < ELLW) ell[(size_t)d * ELLW + slot] = src[e];
  }
}

// ===========================================================================
// gemmW1: G = H @ W1 (NO bias — b1 is added once in agg_stats).
// A-frags direct from row-major bf16 H; C-layout bf16 store (row-major G).
// Used once at startup for G0 = h0 @ W1[0].
// ===========================================================================
__global__ __launch_bounds__(256) void gemmW1(
    const bf16_t* __restrict__ H, const bf16_t* __restrict__ Wsw1,
    bf16_t* __restrict__ G, int nStrips, int N) {
  const int t = threadIdx.x;
  const int wv = t >> 6;
  const int lane = t & 63;
  const int l15 = lane & 15;
  const int quad = lane >> 4;
  const int strip = blockIdx.x * 4 + wv;
  if (strip >= nStrips) return;

  bf16x8 a[4];
  const int row = strip * 16 + l15;
  if (row < N) {
#pragma unroll
    for (int kc = 0; kc < 4; ++kc)
      a[kc] = *(const bf16x8*)(H + (size_t)row * D + kc * 32 + quad * 8);
  } else {
#pragma unroll
    for (int kc = 0; kc < 4; ++kc)
#pragma unroll
      for (int j = 0; j < 8; ++j) a[kc][j] = (bf16_t)0.f;
  }

  floatx4 acc[8];
#pragma unroll
  for (int nt = 0; nt < 8; ++nt) acc[nt] = (floatx4){0.f, 0.f, 0.f, 0.f};
#pragma unroll
  for (int nt = 0; nt < 8; ++nt) {
#pragma unroll
    for (int kc = 0; kc < 4; ++kc) {
      bf16x8 b = *(const bf16x8*)(Wsw1 + (size_t)((nt * 4 + kc) * 64 + lane) * 8);
      acc[nt] = __builtin_amdgcn_mfma_f32_16x16x32_bf16(a[kc], b, acc[nt], 0, 0, 0);
    }
  }

  const int rowBase = strip * 16 + quad * 4;
#pragma unroll
  for (int nt = 0; nt < 8; ++nt) {
    int c = nt * 16 + l15;
#pragma unroll
    for (int r = 0; r < 4; ++r) {
      int rw = rowBase + r;
      if (rw < N) G[(size_t)rw * D + c] = (bf16_t)acc[nt][r];
    }
  }
}

// ===========================================================================
// agg_stats: LINEARITY — aggregate in G-space (G = h@W1):
//   Y[v] = b1 + G[v] + sum_{u in N(v)} G[u]
// Same validated gather (1 node / half-wave, 8-deep pipeline, R5-R7 tuned);
// BN column stats are plain column sums of the Y the lane just produced
// (zero MFMA; each lane owns columns off..off+3 for its node). This kernel
// replaces aggregate AND gemm1_stats.
// ===========================================================================
__global__ __launch_bounds__(256) void agg_stats(
    const bf16_t* __restrict__ G, bf16_t* __restrict__ Y,
    const int* __restrict__ ell, const int* __restrict__ deg,
    const float* __restrict__ bias1, float* __restrict__ stats, int Nn) {
  __shared__ float sred[256];
  const int t = threadIdx.x;
  sred[t] = 0.f;

  const int node = blockIdx.x * 8 + (t >> 5);
  const int s = t & 31;
  const int off = s << 2;            // 4 bf16 = 8 B per lane
  const bool valid = node < Nn;

  floatx4 A0 = {0.f, 0.f, 0.f, 0.f};
  floatx4 A1 = {0.f, 0.f, 0.f, 0.f};
  floatx4 A2 = {0.f, 0.f, 0.f, 0.f};
  floatx4 A3 = {0.f, 0.f, 0.f, 0.f};
  if (valid) {
    int dg = deg[node]; if (dg > ELLW) dg = ELLW;
    const int* nb = ell + (size_t)node * ELLW;
    float4 bv = *(const float4*)(bias1 + off);
    bf16x4 sv = *(const bf16x4*)(G + (size_t)node * D + off);
    A0[0] = bv.x + (float)sv[0]; A0[1] = bv.y + (float)sv[1];
    A0[2] = bv.z + (float)sv[2]; A0[3] = bv.w + (float)sv[3];
    int e = 0;
    for (; e + 8 <= dg; e += 8) {
      int4 ia = *(const int4*)(nb + e);
      int4 ib = *(const int4*)(nb + e + 4);
      bf16x4 v0 = *(const bf16x4*)(G + (size_t)ia.x * D + off);
      bf16x4 v1 = *(const bf16x4*)(G + (size_t)ia.y * D + off);
      bf16x4 v2 = *(const bf16x4*)(G + (size_t)ia.z * D + off);
      bf16x4 v3 = *(const bf16x4*)(G + (size_t)ia.w * D + off);
      bf16x4 v4 = *(const bf16x4*)(G + (size_t)ib.x * D + off);
      bf16x4 v5 = *(const bf16x4*)(G + (size_t)ib.y * D + off);
      bf16x4 v6 = *(const bf16x4*)(G + (size_t)ib.z * D + off);
      bf16x4 v7 = *(const bf16x4*)(G + (size_t)ib.w * D + off);
#pragma unroll
      for (int j = 0; j < 4; ++j) {
        A0[j] += (float)v0[j];
        A1[j] += (float)v1[j];
        A2[j] += (float)v2[j];
        A3[j] += (float)v3[j];
        A0[j] += (float)v4[j];
        A1[j] += (float)v5[j];
        A2[j] += (float)v6[j];
        A3[j] += (float)v7[j];
      }
    }
    for (; e + 4 <= dg; e += 4) {
      int4 i4 = *(const int4*)(nb + e);
      bf16x4 v0 = *(const bf16x4*)(G + (size_t)i4.x * D + off);
      bf16x4 v1 = *(const bf16x4*)(G + (size_t)i4.y * D + off);
      bf16x4 v2 = *(const bf16x4*)(G + (size_t)i4.z * D + off);
      bf16x4 v3 = *(const bf16x4*)(G + (size_t)i4.w * D + off);
#pragma unroll
      for (int j = 0; j < 4; ++j) {
        A0[j] += (float)v0[j];
        A1[j] += (float)v1[j];
        A2[j] += (float)v2[j];
        A3[j] += (float)v3[j];
      }
    }
    for (; e < dg; ++e) {
      bf16x4 v = *(const bf16x4*)(G + (size_t)nb[e] * D + off);
#pragma unroll
      for (int j = 0; j < 4; ++j) A0[j] += (float)v[j];
    }
  }
#pragma unroll
  for (int j = 0; j < 4; ++j) A0[j] += A1[j] + A2[j] + A3[j];

  bf16x4 o;
  o[0] = (bf16_t)A0[0]; o[1] = (bf16_t)A0[1];
  o[2] = (bf16_t)A0[2]; o[3] = (bf16_t)A0[3];
  if (valid) *(bf16x4*)(Y + (size_t)node * D + off) = o;

  // BN stats on the rounded Y (consistent with what mlp2g will read).
  float s4[4], q4[4];
#pragma unroll
  for (int j = 0; j < 4; ++j) {
    float v = valid ? (float)o[j] : 0.f;
    s4[j] = v; q4[j] = v * v;
  }
  // lane s and s+32 of each wave share columns off..off+3
#pragma unroll
  for (int j = 0; j < 4; ++j) {
    s4[j] += __shfl_xor(s4[j], 32);
    q4[j] += __shfl_xor(q4[j], 32);
  }
  if ((t & 63) < 32) {
#pragma unroll
    for (int j = 0; j < 4; ++j) {
      atomicAdd(&sred[off + j], s4[j]);
      atomicAdd(&sred[128 + off + j], q4[j]);
    }
  }
  __syncthreads();
  // XCD-grouped global accumulation (R6: cuts cross-XCD line migration)
  atomicAdd(&stats[((blockIdx.x & (SGRP - 1)) << 8) + t], sred[t]);
}

// ===========================================================================
// mlp2g: stats -> BN coeffs; Y A-frags -> BN+ReLU per-element -> GEMM2 ->
//   last layer: store fp32 h to out.
//   else: relu(h) -> LDS transpose -> G_next = relu(h) @ W1_next (no bias)
//         -> store G_next bf16. h itself never touches memory.
// ===========================================================================
__global__ __launch_bounds__(256) void mlp2g(
    const bf16_t* __restrict__ Y, const float* __restrict__ stats,
    const float* __restrict__ gamma, const float* __restrict__ beta,
    const bf16_t* __restrict__ Wsw2, const float* __restrict__ bias2,
    const bf16_t* __restrict__ Wsw1n, void* __restrict__ outp,
    int nStrips, int N, float invN, int last) {
  __shared__ bf16_t T[64][136];
  __shared__ float abL[256];
  const int t = threadIdx.x;
  const int wv = t >> 6;
  const int lane = t & 63;
  const int l15 = lane & 15;
  const int quad = lane >> 4;
  const int strip = blockIdx.x * 4 + wv;
  const bool active = strip < nStrips;

  // BN coefficients: sum the SGRP per-XCD partials, then fold
  if (t < 128) {
    float s0 = 0.f, q0 = 0.f;
#pragma unroll
    for (int g = 0; g < SGRP; ++g) {
      s0 += stats[(g << 8) + t];
      q0 += stats[(g << 8) + 128 + t];
    }
    float mu = s0 * invN;
    float var = fmaxf(q0 * invN - mu * mu, 0.f);
    float ai = gamma[t] * rsqrtf(var + BN_EPS);
    abL[t] = ai;
    abL[128 + t] = beta[t] - mu * ai;
  }

  // Y A-frags from global (row-major bf16 == A-frag order)
  bf16x8 ay[4];
  const int row = strip * 16 + l15;
  if (active && row < N) {
#pragma unroll
    for (int kc = 0; kc < 4; ++kc)
      ay[kc] = *(const bf16x8*)(Y + (size_t)row * D + kc * 32 + quad * 8);
  } else {
#pragma unroll
    for (int kc = 0; kc < 4; ++kc)
#pragma unroll
      for (int j = 0; j < 8; ++j) ay[kc][j] = (bf16_t)0.f;
  }

  __syncthreads();   // abL ready

  // BN+ReLU per element in A-frag layout: c = kc*32 + quad*8 + j
  bf16x8 a2[4];
#pragma unroll
  for (int kc = 0; kc < 4; ++kc) {
#pragma unroll
    for (int j = 0; j < 8; ++j) {
      int c = kc * 32 + quad * 8 + j;
      float v = fmaxf(fmaf((float)ay[kc][j], abL[c], abL[128 + c]), 0.f);
      a2[kc][j] = (bf16_t)v;
    }
  }

  // GEMM2
  floatx4 acc[8];
#pragma unroll
  for (int nt = 0; nt < 8; ++nt) {
    float bv = bias2[nt * 16 + l15];
    acc[nt] = (floatx4){bv, bv, bv, bv};
  }
#pragma unroll
  for (int nt = 0; nt < 8; ++nt) {
#pragma unroll
    for (int kc = 0; kc < 4; ++kc) {
      bf16x8 b = *(const bf16x8*)(Wsw2 + (size_t)((nt * 4 + kc) * 64 + lane) * 8);
      acc[nt] = __builtin_amdgcn_mfma_f32_16x16x32_bf16(a2[kc], b, acc[nt], 0, 0, 0);
    }
  }

  const int rowBase = strip * 16 + quad * 4;
  if (last) {
    if (!active) return;
    float* out = (float*)outp;
#pragma unroll
    for (int nt = 0; nt < 8; ++nt) {
      int c = nt * 16 + l15;
#pragma unroll
      for (int r = 0; r < 4; ++r) {
        int rw = rowBase + r;
        if (rw < N) out[(size_t)rw * D + c] = acc[nt][r];
      }
    }
    return;
  }

  // relu(h) -> transpose to A-frag order via LDS
  const int lr = wv * 16 + quad * 4;
#pragma unroll
  for (int nt = 0; nt < 8; ++nt) {
    int c = nt * 16 + l15;
#pragma unroll
    for (int r = 0; r < 4; ++r)
      T[lr + r][c] = (bf16_t)fmaxf(acc[nt][r], 0.f);
  }
  __syncthreads();

  bf16x8 ah[4];
#pragma unroll
  for (int kc = 0; kc < 4; ++kc)
    ah[kc] = *(const bf16x8*)&T[wv * 16 + l15][kc * 32 + quad * 8];

  // G_next = relu(h) @ W1_next  (no bias)
#pragma unroll
  for (int nt = 0; nt < 8; ++nt) acc[nt] = (floatx4){0.f, 0.f, 0.f, 0.f};
#pragma unroll
  for (int nt = 0; nt < 8; ++nt) {
#pragma unroll
    for (int kc = 0; kc < 4; ++kc) {
      bf16x8 b = *(const bf16x8*)(Wsw1n + (size_t)((nt * 4 + kc) * 64 + lane) * 8);
      acc[nt] = __builtin_amdgcn_mfma_f32_16x16x32_bf16(ah[kc], b, acc[nt], 0, 0, 0);
    }
  }

  if (!active) return;
  bf16_t* Gout = (bf16_t*)outp;
#pragma unroll
  for (int nt = 0; nt < 8; ++nt) {
    int c = nt * 16 + l15;
#pragma unroll
    for (int r = 0; r < 4; ++r) {
      int rw = rowBase + r;
      if (rw < N) Gout[(size_t)rw * D + c] = (bf16_t)acc[nt][r];
    }
  }
}

// ===========================================================================
extern "C" void kernel_launch(void* const* d_in, const int* in_sizes, int n_in,
                              void* d_out, int out_size, void* d_ws, size_t ws_size,
                              hipStream_t stream) {
  const float* x     = (const float*)d_in[0];
  const float* W1    = (const float*)d_in[1];
  const float* b1    = (const float*)d_in[2];
  const float* gamma = (const float*)d_in[3];
  const float* beta  = (const float*)d_in[4];
  const float* W2    = (const float*)d_in[5];
  const float* b2    = (const float*)d_in[6];
  const int*   ei    = (const int*)d_in[7];

  const int N = in_sizes[0] / D;
  const int E = in_sizes[7] / 2;
  const int* src = ei;
  const int* dst = ei + E;

  char* ws = (char*)d_ws;
  size_t bufBytes = (size_t)N * D * sizeof(bf16_t);        // 12.8 MB
  bf16_t* hb   = (bf16_t*)ws;                               // h0 (bf16)
  bf16_t* Gb   = (bf16_t*)(ws + bufBytes);                  // G = h@W1 (bf16)
  bf16_t* Yb   = (bf16_t*)(ws + 2 * bufBytes);              // Y (bf16)
  int*    ell  = (int*)(ws + 3 * bufBytes);                 // N*64 int = 12.8 MB
  int*    deg  = (int*)((char*)ell + (size_t)N * ELLW * sizeof(int));
  float*  stats = (float*)((char*)deg + (size_t)N * sizeof(int)); // 3*SGRP*256
  bf16_t* Wsw  = (bf16_t*)(stats + 3 * SGRP * 256);         // 6*16384 bf16

  const int n4 = N * D / 4;
  const int prepBlocks = (n4 + 255) / 256;
  const int eb = (E + 255) / 256;
  const int aggBlocks = (N + 7) / 8;
  const int nStrips = (N + 15) / 16;
  const int gemmBlocks = (nStrips + 3) / 4;
  const float invN = 1.f / (float)N;

  prep<<<prepBlocks, 256, 0, stream>>>(x, hb, W1, W2, Wsw, deg, stats, N, n4);
  ell_fill<<<eb, 256, 0, stream>>>(src, dst, deg, ell, E);
  gemmW1<<<gemmBlocks, 256, 0, stream>>>(hb, Wsw, Gb, nStrips, N);

  for (int i = 0; i < 3; ++i) {
    float* st = stats + (size_t)i * SGRP * 256;
    agg_stats<<<aggBlocks, 256, 0, stream>>>(
        Gb, Yb, ell, deg, b1 + (size_t)i * D, st, N);
    void* Ob = (i == 2) ? d_out : (void*)Gb;   // G overwritten in place (read is Y)
    mlp2g<<<gemmBlocks, 256, 0, stream>>>(
        Yb, st, gamma + (size_t)i * D, beta + (size_t)i * D,
        Wsw + (size_t)(i + 3) * 16384, b2 + (size_t)i * D,
        Wsw + (size_t)(i + 1 < 3 ? i + 1 : 0) * 16384,
        Ob, nStrips, N, invN, (i == 2) ? 1 : 0);
  }
}

// Round 10
// 297.908 us; speedup vs baseline: 1.1389x; 1.1389x over previous
//
#include <hip/hip_runtime.h>

#define D 128
#define BN_EPS 1e-5f
#define ELLW 64             // max degree slots (Poisson(12.8): P(deg>64) ~ 1e-24)
#define SGRP 8              // stats accumulator groups (= #XCDs; blockIdx%8 ~ XCD)

typedef __bf16 bf16_t;
typedef __bf16 bf16x8 __attribute__((ext_vector_type(8)));
typedef __bf16 bf16x4 __attribute__((ext_vector_type(4)));
typedef float floatx4 __attribute__((ext_vector_type(4)));

// ===========================================================================
// prep: zero deg[N] + stats[3*SGRP*256], x fp32 -> hb bf16, swizzle weights
// to MFMA B-frag order. Grid covers n4 = N*D/4 (largest range).
// ===========================================================================
__global__ void prep(const float* __restrict__ x, bf16_t* __restrict__ hb,
                     const float* __restrict__ W1, const float* __restrict__ W2,
                     bf16_t* __restrict__ Wsw, int* __restrict__ deg,
                     float* __restrict__ stats, int N, int n4) {
  int i = blockIdx.x * blockDim.x + threadIdx.x;
  if (i < n4) {
    float4 v = ((const float4*)x)[i];
    bf16x4 p;
    p[0] = (bf16_t)v.x; p[1] = (bf16_t)v.y; p[2] = (bf16_t)v.z; p[3] = (bf16_t)v.w;
    *(bf16x4*)(hb + (size_t)4 * i) = p;
  }
  if (i < N) deg[i] = 0;
  if (i < 3 * SGRP * 256) stats[i] = 0.f;
  if (i < 6 * 16384) {
    // B-frag order: lane = quad*16 + (n&15) holds B[k=kc*32+quad*8+j][n]
    int mat = i >> 14;
    int kn = i & 16383;
    int k = kn >> 7;
    int n = kn & 127;
    const float* Wm = (mat < 3) ? (W1 + (size_t)mat * 16384)
                                : (W2 + (size_t)(mat - 3) * 16384);
    float v = Wm[kn];
    int f = ((n >> 4) << 2) | (k >> 5);
    int ln = (((k >> 3) & 3) << 4) | (n & 15);
    int j = k & 7;
    Wsw[(size_t)mat * 16384 + ((f << 6) + ln) * 8 + j] = (bf16_t)v;
  }
}

// ===========================================================================
// ell_fill: one-shot ELL build — atomic slot bump + native 4B scatter.
// ===========================================================================
__global__ void ell_fill(const int* __restrict__ src, const int* __restrict__ dst,
                         int* __restrict__ deg, int* __restrict__ ell, int E) {
  int e = blockIdx.x * blockDim.x + threadIdx.x;
  if (e < E) {
    int d = dst[e];
    int slot = atomicAdd(&deg[d], 1);
    if (slot < ELLW) ell[(size_t)d * ELLW + slot] = src[e];
  }
}

// ===========================================================================
// aggregate: z[v] = h[v] + sum_{u in N(v)} h[u].
// FOUR nodes per wave (quarter-wave of 16 lanes per node, bf16x8 = 16B/lane)
// + 8-deep pipeline -> 32 rows in flight per wave (2x R7). The gather is
// latency*concurrency bound (R8/R9 counters: ~50us, FETCH ~68MB = per-XCD
// compulsory-miss floor, logical ~3.2 TB/s << L2 capability, VALU 20%);
// stream count per wave is the remaining concurrency knob (R5's 1->2
// streams was the biggest gather win; depth beyond 8 was null).
// ===========================================================================
__global__ __launch_bounds__(256) void aggregate(
    const bf16_t* __restrict__ h, bf16_t* __restrict__ z,
    const int* __restrict__ ell, const int* __restrict__ deg, int Nn) {
  int node = blockIdx.x * 16 + (threadIdx.x >> 4);
  if (node >= Nn) return;
  int s = threadIdx.x & 15;
  int off = s << 3;                  // 8 bf16 = 16 B per lane
  int dg = deg[node]; if (dg > ELLW) dg = ELLW;
  const int* nb = ell + (size_t)node * ELLW;

  bf16x8 sv = *(const bf16x8*)(h + (size_t)node * D + off);
  float A[8], B[8];
#pragma unroll
  for (int j = 0; j < 8; ++j) { A[j] = (float)sv[j]; B[j] = 0.f; }

  int e = 0;
  for (; e + 8 <= dg; e += 8) {
    int4 ia = *(const int4*)(nb + e);
    int4 ib = *(const int4*)(nb + e + 4);
    bf16x8 v0 = *(const bf16x8*)(h + (size_t)ia.x * D + off);
    bf16x8 v1 = *(const bf16x8*)(h + (size_t)ia.y * D + off);
    bf16x8 v2 = *(const bf16x8*)(h + (size_t)ia.z * D + off);
    bf16x8 v3 = *(const bf16x8*)(h + (size_t)ia.w * D + off);
    bf16x8 v4 = *(const bf16x8*)(h + (size_t)ib.x * D + off);
    bf16x8 v5 = *(const bf16x8*)(h + (size_t)ib.y * D + off);
    bf16x8 v6 = *(const bf16x8*)(h + (size_t)ib.z * D + off);
    bf16x8 v7 = *(const bf16x8*)(h + (size_t)ib.w * D + off);
#pragma unroll
    for (int j = 0; j < 8; ++j) {
      A[j] += (float)v0[j]; B[j] += (float)v1[j];
      A[j] += (float)v2[j]; B[j] += (float)v3[j];
      A[j] += (float)v4[j]; B[j] += (float)v5[j];
      A[j] += (float)v6[j]; B[j] += (float)v7[j];
    }
  }
  for (; e + 4 <= dg; e += 4) {
    int4 i4 = *(const int4*)(nb + e);
    bf16x8 v0 = *(const bf16x8*)(h + (size_t)i4.x * D + off);
    bf16x8 v1 = *(const bf16x8*)(h + (size_t)i4.y * D + off);
    bf16x8 v2 = *(const bf16x8*)(h + (size_t)i4.z * D + off);
    bf16x8 v3 = *(const bf16x8*)(h + (size_t)i4.w * D + off);
#pragma unroll
    for (int j = 0; j < 8; ++j) {
      A[j] += (float)v0[j]; B[j] += (float)v1[j];
      A[j] += (float)v2[j]; B[j] += (float)v3[j];
    }
  }
  for (; e < dg; ++e) {
    bf16x8 v = *(const bf16x8*)(h + (size_t)nb[e] * D + off);
#pragma unroll
    for (int j = 0; j < 8; ++j) A[j] += (float)v[j];
  }

  bf16x8 o;
#pragma unroll
  for (int j = 0; j < 8; ++j) o[j] = (bf16_t)(A[j] + B[j]);
  *(bf16x8*)(z + (size_t)node * D + off) = o;
}

// ===========================================================================
// gemm1_stats: GEMM1 (Z @ W1 + b1) -> BN column stats ONLY (no Y write;
// mlp2r recomputes GEMM1 bit-identically). Stats atomics XCD-grouped
// (stats[blockIdx%8][256]) — R4-R6: cost scales with cross-XCD same-address
// RMW line migration, not per-line serialization.
// ===========================================================================
__global__ __launch_bounds__(256) void gemm1_stats(
    const bf16_t* __restrict__ Z, const bf16_t* __restrict__ Wsw1,
    const float* __restrict__ bias1, float* __restrict__ stats,
    int nStrips, int N) {
  __shared__ float sred[256];
  const int t = threadIdx.x;
  const int lane = t & 63;
  const int l15 = lane & 15;
  const int quad = lane >> 4;
  const int strip = blockIdx.x * 4 + (t >> 6);
  const bool active = strip < nStrips;

  sred[t] = 0.f;
  __syncthreads();

  bf16x8 a[4];
  const int row = strip * 16 + l15;
  if (active && row < N) {
#pragma unroll
    for (int kc = 0; kc < 4; ++kc)
      a[kc] = *(const bf16x8*)(Z + (size_t)row * D + kc * 32 + quad * 8);
  } else {
#pragma unroll
    for (int kc = 0; kc < 4; ++kc)
#pragma unroll
      for (int j = 0; j < 8; ++j) a[kc][j] = (bf16_t)0.f;
  }

  floatx4 acc[8];
#pragma unroll
  for (int nt = 0; nt < 8; ++nt) {
    float bv = bias1[nt * 16 + l15];
    acc[nt] = (floatx4){bv, bv, bv, bv};
  }
#pragma unroll
  for (int nt = 0; nt < 8; ++nt) {
#pragma unroll
    for (int kc = 0; kc < 4; ++kc) {
      bf16x8 b = *(const bf16x8*)(Wsw1 + (size_t)((nt * 4 + kc) * 64 + lane) * 8);
      acc[nt] = __builtin_amdgcn_mfma_f32_16x16x32_bf16(a[kc], b, acc[nt], 0, 0, 0);
    }
  }

  // BN stats: C/D layout col = nt*16+l15, row = quad*4+r
  const int rowBase = strip * 16 + quad * 4;
#pragma unroll
  for (int nt = 0; nt < 8; ++nt) {
    int c = nt * 16 + l15;
    float s = 0.f, q = 0.f;
    if (active) {
#pragma unroll
      for (int r = 0; r < 4; ++r) {
        if (rowBase + r < N) {
          float v = acc[nt][r];
          s += v; q += v * v;
        }
      }
    }
    s += __shfl_xor(s, 16); s += __shfl_xor(s, 32);
    q += __shfl_xor(q, 16); q += __shfl_xor(q, 32);
    if (quad == 0) {
      atomicAdd(&sred[c], s);
      atomicAdd(&sred[128 + c], q);
    }
  }
  __syncthreads();
  atomicAdd(&stats[((blockIdx.x & (SGRP - 1)) << 8) + t], sred[t]);
}

// ===========================================================================
// mlp2r: sum SGRP stats partials -> BN coeffs; recompute GEMM1 from Z
// (bit-identical) -> BN+ReLU in C-layout -> LDS transpose to A-frags ->
// GEMM2 -> store. All waves run all barriers; only global stores guarded.
// ===========================================================================
__global__ __launch_bounds__(256) void mlp2r(
    const bf16_t* __restrict__ Z, const float* __restrict__ stats,
    const float* __restrict__ gamma, const float* __restrict__ beta,
    const bf16_t* __restrict__ Wsw1, const float* __restrict__ bias1,
    const bf16_t* __restrict__ Wsw2, const float* __restrict__ bias2,
    void* __restrict__ outp, int nStrips, int N, float invN,
    int relu_out, int fp32_out) {
  __shared__ bf16_t T[64][136];
  __shared__ float abL[256];
  const int t = threadIdx.x;
  const int wv = t >> 6;
  const int lane = t & 63;
  const int l15 = lane & 15;
  const int quad = lane >> 4;
  const int strip = blockIdx.x * 4 + wv;
  const bool active = strip < nStrips;

  // BN coefficients: sum the SGRP per-XCD partials, then fold
  if (t < 128) {
    float s0 = 0.f, q0 = 0.f;
#pragma unroll
    for (int g = 0; g < SGRP; ++g) {
      s0 += stats[(g << 8) + t];
      q0 += stats[(g << 8) + 128 + t];
    }
    float mu = s0 * invN;
    float var = fmaxf(q0 * invN - mu * mu, 0.f);
    float ai = gamma[t] * rsqrtf(var + BN_EPS);
    abL[t] = ai;
    abL[128 + t] = beta[t] - mu * ai;
  }

  // ---- GEMM1 recompute ----
  bf16x8 a[4];
  const int row = strip * 16 + l15;
  if (active && row < N) {
#pragma unroll
    for (int kc = 0; kc < 4; ++kc)
      a[kc] = *(const bf16x8*)(Z + (size_t)row * D + kc * 32 + quad * 8);
  } else {
#pragma unroll
    for (int kc = 0; kc < 4; ++kc)
#pragma unroll
      for (int j = 0; j < 8; ++j) a[kc][j] = (bf16_t)0.f;
  }

  floatx4 acc[8];
#pragma unroll
  for (int nt = 0; nt < 8; ++nt) {
    float bv = bias1[nt * 16 + l15];
    acc[nt] = (floatx4){bv, bv, bv, bv};
  }
#pragma unroll
  for (int nt = 0; nt < 8; ++nt) {
#pragma unroll
    for (int kc = 0; kc < 4; ++kc) {
      bf16x8 b = *(const bf16x8*)(Wsw1 + (size_t)((nt * 4 + kc) * 64 + lane) * 8);
      acc[nt] = __builtin_amdgcn_mfma_f32_16x16x32_bf16(a[kc], b, acc[nt], 0, 0, 0);
    }
  }

  __syncthreads();   // abL ready

  // ---- BN+ReLU in C-layout, transpose to A-frag order via LDS ----
  float bnA[8], bnB[8];
#pragma unroll
  for (int nt = 0; nt < 8; ++nt) {
    int c = nt * 16 + l15;
    bnA[nt] = abL[c];
    bnB[nt] = abL[128 + c];
  }

  const int lr = wv * 16 + quad * 4;
#pragma unroll
  for (int nt = 0; nt < 8; ++nt) {
    int c = nt * 16 + l15;
#pragma unroll
    for (int r = 0; r < 4; ++r)
      T[lr + r][c] = (bf16_t)fmaxf(fmaf(acc[nt][r], bnA[nt], bnB[nt]), 0.f);
  }
  __syncthreads();

  bf16x8 a2[4];
#pragma unroll
  for (int kc = 0; kc < 4; ++kc)
    a2[kc] = *(const bf16x8*)&T[wv * 16 + l15][kc * 32 + quad * 8];

  // ---- GEMM2 ----
#pragma unroll
  for (int nt = 0; nt < 8; ++nt) {
    float bv = bias2[nt * 16 + l15];
    acc[nt] = (floatx4){bv, bv, bv, bv};
  }
#pragma unroll
  for (int nt = 0; nt < 8; ++nt) {
#pragma unroll
    for (int kc = 0; kc < 4; ++kc) {
      bf16x8 b = *(const bf16x8*)(Wsw2 + (size_t)((nt * 4 + kc) * 64 + lane) * 8);
      acc[nt] = __builtin_amdgcn_mfma_f32_16x16x32_bf16(a2[kc], b, acc[nt], 0, 0, 0);
    }
  }

  if (!active) return;
  const int rowBase = strip * 16 + quad * 4;
  if (fp32_out) {
    float* out = (float*)outp;
#pragma unroll
    for (int nt = 0; nt < 8; ++nt) {
      int c = nt * 16 + l15;
#pragma unroll
      for (int r = 0; r < 4; ++r) {
        int rw = rowBase + r;
        if (rw < N) {
          float v = acc[nt][r];
          if (relu_out) v = fmaxf(v, 0.f);
          out[(size_t)rw * D + c] = v;
        }
      }
    }
  } else {
    bf16_t* out = (bf16_t*)outp;
#pragma unroll
    for (int nt = 0; nt < 8; ++nt) {
      int c = nt * 16 + l15;
#pragma unroll
      for (int r = 0; r < 4; ++r) {
        int rw = rowBase + r;
        if (rw < N) {
          float v = acc[nt][r];
          if (relu_out) v = fmaxf(v, 0.f);
          out[(size_t)rw * D + c] = (bf16_t)v;
        }
      }
    }
  }
}

// ===========================================================================
extern "C" void kernel_launch(void* const* d_in, const int* in_sizes, int n_in,
                              void* d_out, int out_size, void* d_ws, size_t ws_size,
                              hipStream_t stream) {
  const float* x     = (const float*)d_in[0];
  const float* W1    = (const float*)d_in[1];
  const float* b1    = (const float*)d_in[2];
  const float* gamma = (const float*)d_in[3];
  const float* beta  = (const float*)d_in[4];
  const float* W2    = (const float*)d_in[5];
  const float* b2    = (const float*)d_in[6];
  const int*   ei    = (const int*)d_in[7];

  const int N = in_sizes[0] / D;
  const int E = in_sizes[7] / 2;
  const int* src = ei;
  const int* dst = ei + E;

  char* ws = (char*)d_ws;
  size_t bufBytes = (size_t)N * D * sizeof(bf16_t);        // 12.8 MB
  bf16_t* hb   = (bf16_t*)ws;                               // h (bf16)
  bf16_t* zb   = (bf16_t*)(ws + bufBytes);                  // z (bf16)
  int*    ell  = (int*)(ws + 2 * bufBytes);                 // N*64 int = 12.8 MB
  int*    deg  = (int*)((char*)ell + (size_t)N * ELLW * sizeof(int));
  float*  stats = (float*)((char*)deg + (size_t)N * sizeof(int)); // 3*SGRP*256
  bf16_t* Wsw  = (bf16_t*)(stats + 3 * SGRP * 256);         // 6*16384 bf16

  const int n4 = N * D / 4;
  const int prepBlocks = (n4 + 255) / 256;
  const int eb = (E + 255) / 256;
  const int aggBlocks = (N + 15) / 16;
  const int nStrips = (N + 15) / 16;
  const int gemmBlocks = (nStrips + 3) / 4;
  const float invN = 1.f / (float)N;

  prep<<<prepBlocks, 256, 0, stream>>>(x, hb, W1, W2, Wsw, deg, stats, N, n4);
  ell_fill<<<eb, 256, 0, stream>>>(src, dst, deg, ell, E);

  for (int i = 0; i < 3; ++i) {
    float* st = stats + (size_t)i * SGRP * 256;
    aggregate<<<aggBlocks, 256, 0, stream>>>(hb, zb, ell, deg, N);
    gemm1_stats<<<gemmBlocks, 256, 0, stream>>>(
        zb, Wsw + (size_t)i * 16384, b1 + (size_t)i * D, st, nStrips, N);
    void* Ob = (i == 2) ? d_out : (void*)hb;
    mlp2r<<<gemmBlocks, 256, 0, stream>>>(
        zb, st, gamma + (size_t)i * D, beta + (size_t)i * D,
        Wsw + (size_t)i * 16384, b1 + (size_t)i * D,
        Wsw + (size_t)(i + 3) * 16384, b2 + (size_t)i * D,
        Ob, nStrips, N, invN, (i < 2) ? 1 : 0, (i == 2) ? 1 : 0);
  }
}